// Round 17
// baseline (128.599 us; speedup 1.0000x reference)
//
#include <hip/hip_runtime.h>
#include <stdint.h>

#define DM    768
#define NH    12
#define HD    64
#define BATCH 4
#define SEQ   2048
#define NTOK  (BATCH*SEQ)   // 8192

typedef unsigned int   u32;
typedef unsigned short u16;
using bf16x8 = __attribute__((ext_vector_type(8))) short;
using f32x4  = __attribute__((ext_vector_type(4))) float;

// softmax runs in exp2 domain: Q pre-scaled by (1/8)*log2(e)
#define QSCALE 0.18033688011112042f

__device__ __forceinline__ u16 f2bf(float f) {
    u32 u = __float_as_uint(f);
    u = (u + 0x7FFFu + ((u >> 16) & 1u)) >> 16;
    return (u16)u;
}

__device__ __forceinline__ u32 pkbf(float a, float b) {
    u32 r;
    asm("v_cvt_pk_bf16_f32 %0, %1, %2" : "=v"(r) : "v"(a), "v"(b));
    return r;
}

template <int N>
__device__ __forceinline__ void waitvm() {
    if constexpr (N == 0)      asm volatile("s_waitcnt vmcnt(0)" ::: "memory");
    else if constexpr (N == 4) asm volatile("s_waitcnt vmcnt(4)" ::: "memory");
    else if constexpr (N == 5) asm volatile("s_waitcnt vmcnt(5)" ::: "memory");
    else if constexpr (N == 8) asm volatile("s_waitcnt vmcnt(8)" ::: "memory");
    else if constexpr (N == 9) asm volatile("s_waitcnt vmcnt(9)" ::: "memory");
    else static_assert(N == 0 || N == 4 || N == 5 || N == 8 || N == 9, "add literal");
}

__device__ __forceinline__ void gload_lds16(const void* gptr, void* ldsptr) {
    __builtin_amdgcn_global_load_lds(
        (__attribute__((address_space(1))) const u32*)gptr,
        (__attribute__((address_space(3))) u32*)ldsptr, 16, 0, 0);
}

__device__ __forceinline__ float vmax4(f32x4 v) {
    return fmaxf(fmaxf(v[0], v[1]), fmaxf(v[2], v[3]));
}

// ------- fused prep: x fp32->bf16 (blocks 0..6143) + 4 weight transposes -------
__global__ void prep(const float* __restrict__ x, u16* __restrict__ xb,
                     const float* __restrict__ wq, const float* __restrict__ wk,
                     const float* __restrict__ wv, const float* __restrict__ wo,
                     u16* __restrict__ Wt, u16* __restrict__ Wto) {
    __shared__ float tile[32][33];
    const int blk = blockIdx.x, t = threadIdx.x;
    if (blk < 6144) {                   // x convert: 6144*256 float4 = all of x
        int i = blk * 256 + t;
        float4 v = ((const float4*)x)[i];
        ushort4 o;
        o.x = f2bf(v.x); o.y = f2bf(v.y); o.z = f2bf(v.z); o.w = f2bf(v.w);
        ((ushort4*)xb)[i] = o;
        return;
    }
    int r = blk - 6144;                 // 2304 transpose blocks: z*576 + by*24 + bx
    int z = r / 576;  r -= z * 576;
    int by = r / 24, bx = r - by * 24;
    const float* W = (z == 0) ? wq : (z == 1) ? wk : (z == 2) ? wv : wo;
    u16* D = (z < 3) ? (Wt + (size_t)z * DM * DM) : Wto;
    int tx = t & 31, ty = t >> 5;       // 32 x 8
    int x0 = bx * 32, y0 = by * 32;
    #pragma unroll
    for (int i = 0; i < 32; i += 8)
        tile[ty + i][tx] = W[(size_t)(y0 + ty + i) * DM + x0 + tx];
    __syncthreads();
    #pragma unroll
    for (int i = 0; i < 32; i += 8)
        D[(size_t)(x0 + ty + i) * DM + y0 + tx] = f2bf(tile[tx][ty + i]);
}

// ---- bf16 MFMA GEMM, 2-tiles-ahead pipeline with counted vmcnt (T3/T4) ----
// MODE 0: BM=256, BN=288, BK=32 (LDS 68 KB -> 2 blocks/CU), grid 32x8=256.
// MODE 1: BM=128, BN=192, BK=64 (LDS 80 KB -> 2 blocks/CU), grid 64x4=256.
// XOR swizzle within each row's chunks (4 chunks at BK=32, 8 at BK=64).
template <int MODE>
__global__ __launch_bounds__(512, 2)
void gemm_pipe(const u16* __restrict__ A, const u16* __restrict__ Bt,
               const float* __restrict__ b0, const float* __restrict__ b1,
               const float* __restrict__ b2,
               u16* __restrict__ Qo, u16* __restrict__ Ko, u16* __restrict__ Vto,
               float* __restrict__ Out)
{
    constexpr int BM = (MODE == 0) ? 256 : 128;
    constexpr int BN = (MODE == 0) ? 288 : 192;
    constexpr int BK = (MODE == 0) ? 32 : 64;
    constexpr int NKT = DM / BK;                // 24 / 12
    constexpr int MF = 4;
    constexpr int NF = (MODE == 0) ? 9 : 3;

    __shared__ u16 As[2][BM][BK];
    __shared__ u16 Bs[2][BN][BK];

    const int t = threadIdx.x;
    const int w = t >> 6, l = t & 63;
    const int l15 = l & 15, lg = l >> 4;
    const int m0 = blockIdx.x * BM;
    const int n0 = blockIdx.y * BN;
    const int waveM = ((MODE == 0) ? (w >> 1) : (w >> 2)) * 64;
    const int waveN = (MODE == 0) ? (w & 1) * 144 : (w & 3) * 48;

    f32x4 zf = {0.f, 0.f, 0.f, 0.f};
    f32x4 acc[MF][NF];
    #pragma unroll
    for (int i = 0; i < MF; ++i)
        #pragma unroll
        for (int j = 0; j < NF; ++j) acc[i][j] = zf;

    const u16* Arow0 = A  + (size_t)m0 * DM;
    const u16* Brow0 = Bt + (size_t)n0 * DM;

    auto stage = [&](int d, int k0) {
        if constexpr (MODE == 0) {
            // A: 256x32 = 1024 chunks, 2/thread; B: 288x32 = 1152, 2/thread + t<128
            #pragma unroll
            for (int i = 0; i < 2; ++i) {
                int f = i * 512 + t;
                int row = f >> 2, c = f & 3;
                int gc = c ^ (row & 3);
                gload_lds16(Arow0 + (size_t)row * DM + k0 + gc * 8, &As[d][row][c * 8]);
            }
            #pragma unroll
            for (int i = 0; i < 2; ++i) {
                int f = i * 512 + t;
                int row = f >> 2, c = f & 3;
                int gc = c ^ (row & 3);
                gload_lds16(Brow0 + (size_t)row * DM + k0 + gc * 8, &Bs[d][row][c * 8]);
            }
            if (t < 128) {
                int f = 1024 + t;
                int row = f >> 2, c = f & 3;
                int gc = c ^ (row & 3);
                gload_lds16(Brow0 + (size_t)row * DM + k0 + gc * 8, &Bs[d][row][c * 8]);
            }
        } else {
            #pragma unroll
            for (int i = 0; i < 2; ++i) {           // A: 128x64 = 1024 chunks
                int f = i * 512 + t;
                int row = f >> 3, c = f & 7;
                int gc = c ^ (row & 7);
                gload_lds16(Arow0 + (size_t)row * DM + k0 + gc * 8, &As[d][row][c * 8]);
            }
            #pragma unroll
            for (int i = 0; i < 3; ++i) {           // B: 192x64 = 1536 chunks
                int f = i * 512 + t;
                int row = f >> 3, c = f & 7;
                int gc = c ^ (row & 7);
                gload_lds16(Brow0 + (size_t)row * DM + k0 + gc * 8, &Bs[d][row][c * 8]);
            }
        }
    };
    auto wait_tile = [&]() {                        // tile t done, t+1 in flight
        if constexpr (MODE == 0) {
            if (w < 2) waitvm<5>(); else waitvm<4>();
        } else {
            waitvm<5>();
        }
    };
    auto phase = [&](int d, int kk) {
        const int ch = (MODE == 0) ? ((lg ^ (l15 & 3)) * 8)
                                   : (((kk * 4 + lg) ^ (l15 & 7)) * 8);
        bf16x8 af[MF], bfr[NF];
        #pragma unroll
        for (int m = 0; m < MF; ++m)
            af[m] = *(const bf16x8*)&As[d][waveM + m * 16 + l15][ch];
        #pragma unroll
        for (int n = 0; n < NF; ++n)
            bfr[n] = *(const bf16x8*)&Bs[d][waveN + n * 16 + l15][ch];
        __builtin_amdgcn_s_setprio(1);
        #pragma unroll
        for (int m = 0; m < MF; ++m)
            #pragma unroll
            for (int n = 0; n < NF; ++n)
                acc[m][n] = __builtin_amdgcn_mfma_f32_16x16x32_bf16(af[m], bfr[n], acc[m][n], 0, 0, 0);
        __builtin_amdgcn_s_setprio(0);
    };

    stage(0, 0);
    stage(1, BK);

    for (int tt = 0; tt < NKT - 1; ++tt) {
        const int c = tt & 1;
        wait_tile();
        __builtin_amdgcn_s_barrier();
        __builtin_amdgcn_sched_barrier(0);
        if constexpr (MODE == 0) {
            phase(c, 0);
        } else {
            phase(c, 0);
            phase(c, 1);
        }
        __builtin_amdgcn_sched_barrier(0);
        __builtin_amdgcn_s_barrier();
        __builtin_amdgcn_sched_barrier(0);
        if (tt + 2 < NKT) stage(c, (tt + 2) * BK);
    }
    {
        waitvm<0>();
        __builtin_amdgcn_s_barrier();
        __builtin_amdgcn_sched_barrier(0);
        if constexpr (MODE == 0) {
            phase((NKT - 1) & 1, 0);
        } else {
            phase((NKT - 1) & 1, 0);
            phase((NKT - 1) & 1, 1);
        }
    }

    if (MODE == 1) {
        #pragma unroll
        for (int m = 0; m < MF; ++m) {
            int grow = m0 + waveM + m * 16 + lg * 4;
            #pragma unroll
            for (int n = 0; n < NF; ++n) {
                int gcol = n0 + waveN + n * 16 + l15;
                float bias = b0[gcol];
                #pragma unroll
                for (int r = 0; r < 4; ++r)
                    Out[(size_t)(grow + r) * DM + gcol] = acc[m][n][r] + bias;
            }
        }
    } else {
        #pragma unroll
        for (int m = 0; m < MF; ++m) {
            int grow = m0 + waveM + m * 16 + lg * 4;
            int bb = grow >> 11, ss = grow & 2047;
            #pragma unroll
            for (int n = 0; n < NF; ++n) {
                int nstart = n0 + waveN + n * 16;
                int which = nstart / DM;
                int cbase = nstart - which * DM + l15;
                int h = cbase >> 6, hd = cbase & 63;
                if (which == 0) {
                    float bias = b0[cbase];
                    #pragma unroll
                    for (int r = 0; r < 4; ++r)
                        Qo[(((size_t)bb * NH + h) * SEQ + (ss + r)) * HD + hd] =
                            f2bf((acc[m][n][r] + bias) * QSCALE);
                } else if (which == 1) {
                    float bias = b1[cbase];
                    #pragma unroll
                    for (int r = 0; r < 4; ++r)
                        Ko[(((size_t)bb * NH + h) * SEQ + (ss + r)) * HD + hd] =
                            f2bf(acc[m][n][r] + bias);
                } else {
                    float bias = b2[cbase];
                    u32 lo = pkbf(acc[m][n][0] + bias, acc[m][n][1] + bias);
                    u32 hi = pkbf(acc[m][n][2] + bias, acc[m][n][3] + bias);
                    *(int2*)&Vto[(((size_t)bb * NH + h) * HD + hd) * SEQ + ss] =
                        make_int2((int)lo, (int)hi);
                }
            }
        }
    }
}

// ---------------- causal flash attention v6 (frozen; 57.0-57.3 us) ----------------
__global__ __launch_bounds__(512, 4)
void attn_fwd(const u16* __restrict__ Q, const u16* __restrict__ K_,
              const u16* __restrict__ Vt, u16* __restrict__ ctx)
{
    __shared__ u16 Ks[2][128][64];      // [key][d]
    __shared__ u16 Vs[2][64][128];      // [d][key]

    const int t = threadIdx.x, w = t >> 6, l = t & 63;
    const int l15 = l & 15, lg = l >> 4;
    const int sw = l15 & 7;             // read-side swizzle key
    const int bx = blockIdx.x;
    const int ord = bx / 48;            // ascending => q16 descending (LPT dispatch)
    const int bh  = bx - ord * 48;
    const int q16 = 15 - ord;           // 128-row strip index
    const int b = bh / NH, h = bh - b * NH;
    const int wrow0 = q16 * 128 + w * 16;
    const int niter = q16 + 1;          // 128-key macro-tiles

    const u16* Qp = Q + ((size_t)bh * SEQ + wrow0 + l15) * HD;
    bf16x8 qf0 = *(const bf16x8*)(Qp + lg * 8);
    bf16x8 qf1 = *(const bf16x8*)(Qp + 32 + lg * 8);

    f32x4 zf = {0.f, 0.f, 0.f, 0.f};
    f32x4 acc[4];
    #pragma unroll
    for (int d = 0; d < 4; ++d) acc[d] = zf;
    float mi = -INFINITY, li = 0.f;

    const u16* Kbh = K_ + (size_t)bh * SEQ * HD;
    const u16* Vbh = Vt + (size_t)bh * HD * SEQ;

    auto stage = [&](int d, int j0) {
        #pragma unroll
        for (int i = 0; i < 2; ++i) {
            int f = i * 512 + t;
            int row = f >> 3, c = f & 7;
            gload_lds16(Kbh + (size_t)(j0 + row) * HD + (c ^ (row & 7)) * 8,
                        (u16*)Ks[d] + (size_t)f * 8);
        }
        #pragma unroll
        for (int i = 0; i < 2; ++i) {
            int f = i * 512 + t;
            int r = f >> 4, c = f & 15;
            gload_lds16(Vbh + (size_t)r * SEQ + j0 + (((c & 8) | ((c ^ r) & 7))) * 8,
                        (u16*)Vs[d] + (size_t)f * 8);
        }
    };

    stage(0, 0);
    stage(1, 128);                      // keys 128..255 always exist (S=2048)

    for (int jt = 0; jt < niter; ++jt) {
        const int cur = jt & 1;
        const int j0 = jt << 7;
        if (jt < niter - 1) waitvm<4>(); else waitvm<0>();
        __builtin_amdgcn_s_barrier();
        __builtin_amdgcn_sched_barrier(0);
        const u16 (*Kc)[64]  = Ks[cur];
        const u16 (*Vc)[128] = Vs[cur];
        #pragma unroll
        for (int hk = 0; hk < 2; ++hk) {
            const int j0h = j0 + hk * 64;
            if (j0h <= wrow0 + 15) {    // wave-uniform causal skip per half
                f32x4 s0[4];
                __builtin_amdgcn_s_setprio(1);
                #pragma unroll
                for (int nt = 0; nt < 4; ++nt) {
                    const u16* krow = Kc[hk * 64 + nt * 16 + l15];
                    bf16x8 kf0 = *(const bf16x8*)&krow[(lg ^ sw) * 8];
                    bf16x8 kf1 = *(const bf16x8*)&krow[((4 + lg) ^ sw) * 8];
                    f32x4 a = zf;
                    a = __builtin_amdgcn_mfma_f32_16x16x32_bf16(kf0, qf0, a, 0, 0, 0);
                    a = __builtin_amdgcn_mfma_f32_16x16x32_bf16(kf1, qf1, a, 0, 0, 0);
                    s0[nt] = a;
                }
                __builtin_amdgcn_s_setprio(0);
                if (j0h + 63 > wrow0) { // diagonal region: per-element causal mask
                    #pragma unroll
                    for (int nt = 0; nt < 4; ++nt) {
                        int kb = j0h + nt * 16 + lg * 4;
                        #pragma unroll
                        for (int r = 0; r < 4; ++r)
                            if (kb + r > wrow0 + l15) s0[nt][r] = -INFINITY;
                    }
                }
                float pm = fmaxf(fmaxf(vmax4(s0[0]), vmax4(s0[1])), fmaxf(vmax4(s0[2]), vmax4(s0[3])));
                pm = fmaxf(pm, __shfl_xor(pm, 16));
                pm = fmaxf(pm, __shfl_xor(pm, 32));
                if (!__all(pm <= mi + 8.f)) {   // defer-max (T13)
                    float mn = fmaxf(mi, pm);
                    float so = __builtin_amdgcn_exp2f(mi - mn);
                    mi = mn;
                    li *= so;
                    float a0 = __shfl(so, lg * 4 + 0), a1 = __shfl(so, lg * 4 + 1);
                    float a2 = __shfl(so, lg * 4 + 2), a3 = __shfl(so, lg * 4 + 3);
                    #pragma unroll
                    for (int d = 0; d < 4; ++d) {
                        acc[d][0] *= a0; acc[d][1] *= a1;
                        acc[d][2] *= a2; acc[d][3] *= a3;
                    }
                }
                u32 dwa[8];
                float rs = 0.f;
                #pragma unroll
                for (int nt = 0; nt < 4; ++nt) {
                    float p0 = __builtin_amdgcn_exp2f(s0[nt][0] - mi);
                    float p1 = __builtin_amdgcn_exp2f(s0[nt][1] - mi);
                    float p2 = __builtin_amdgcn_exp2f(s0[nt][2] - mi);
                    float p3 = __builtin_amdgcn_exp2f(s0[nt][3] - mi);
                    rs += (p0 + p1) + (p2 + p3);
                    dwa[nt * 2] = pkbf(p0, p1); dwa[nt * 2 + 1] = pkbf(p2, p3);
                }
                rs += __shfl_xor(rs, 16);
                rs += __shfl_xor(rs, 32);
                li += rs;
                bf16x8 pa0 = __builtin_bit_cast(bf16x8, make_int4((int)dwa[0], (int)dwa[1], (int)dwa[2], (int)dwa[3]));
                bf16x8 pa1 = __builtin_bit_cast(bf16x8, make_int4((int)dwa[4], (int)dwa[5], (int)dwa[6], (int)dwa[7]));
                const int o4 = (lg & 1) * 4, c0 = lg >> 1;
                __builtin_amdgcn_s_setprio(1);
                #pragma unroll
                for (int d = 0; d < 4; ++d) {
                    const u16* vrow = Vc[d * 16 + l15] + hk * 64;
                    int2 v0 = *(const int2*)(vrow + (((c0 + 0) ^ sw) * 8 + o4));
                    int2 v1 = *(const int2*)(vrow + (((c0 + 2) ^ sw) * 8 + o4));
                    int2 v2 = *(const int2*)(vrow + (((c0 + 4) ^ sw) * 8 + o4));
                    int2 v3 = *(const int2*)(vrow + (((c0 + 6) ^ sw) * 8 + o4));
                    bf16x8 vf0 = __builtin_bit_cast(bf16x8, make_int4(v0.x, v0.y, v1.x, v1.y));
                    bf16x8 vf1 = __builtin_bit_cast(bf16x8, make_int4(v2.x, v2.y, v3.x, v3.y));
                    acc[d] = __builtin_amdgcn_mfma_f32_16x16x32_bf16(pa0, vf0, acc[d], 0, 0, 0);
                    acc[d] = __builtin_amdgcn_mfma_f32_16x16x32_bf16(pa1, vf1, acc[d], 0, 0, 0);
                }
                __builtin_amdgcn_s_setprio(0);
            }
        }
        if (jt < niter - 1) {
            __builtin_amdgcn_s_barrier();            // all waves done reading buf cur
            __builtin_amdgcn_sched_barrier(0);
            if (jt + 2 < niter) stage(cur, (jt + 2) << 7);
        }
    }

    // epilogue: ctx [B][S][768] bf16
    float e0 = 1.0f / __shfl(li, lg * 4 + 0), e1 = 1.0f / __shfl(li, lg * 4 + 1);
    float e2 = 1.0f / __shfl(li, lg * 4 + 2), e3 = 1.0f / __shfl(li, lg * 4 + 3);
    #pragma unroll
    for (int r = 0; r < 4; ++r) {
        float f0 = (r == 0) ? e0 : (r == 1) ? e1 : (r == 2) ? e2 : e3;
        int s = wrow0 + lg * 4 + r;
        size_t base = ((size_t)b * SEQ + s) * DM + h * HD;
        #pragma unroll
        for (int d = 0; d < 4; ++d)
            ctx[base + d * 16 + l15] = f2bf(acc[d][r] * f0);
    }
}

extern "C" void kernel_launch(void* const* d_in, const int* in_sizes, int n_in,
                              void* d_out, int out_size, void* d_ws, size_t ws_size,
                              hipStream_t stream) {
    const float* x  = (const float*)d_in[0];
    const float* Wq = (const float*)d_in[1];
    const float* bq = (const float*)d_in[2];
    const float* Wk = (const float*)d_in[3];
    const float* bk = (const float*)d_in[4];
    const float* Wv = (const float*)d_in[5];
    const float* bv = (const float*)d_in[6];
    const float* Wo = (const float*)d_in[7];
    const float* bo = (const float*)d_in[8];
    float* out = (float*)d_out;

    char* ws = (char*)d_ws;
    u16* xb  = (u16*)(ws);                    // 8192*768*2      = 12,582,912
    u16* Wt  = (u16*)(ws + 12582912);         // 2304*768*2      =  3,538,944
    u16* Wto = (u16*)(ws + 16121856);         // 768*768*2       =  1,179,648
    u16* Qw  = (u16*)(ws + 17301504);         // [BH][S][64]     = 12,582,912
    u16* Kw  = (u16*)(ws + 29884416);         // [BH][S][64]     = 12,582,912
    u16* Vtw = (u16*)(ws + 42467328);         // [BH][64][S]     = 12,582,912
    u16* ctx = (u16*)(ws + 55050240);         // [B][S][768]     = 12,582,912

    prep<<<6144 + 2304, 256, 0, stream>>>(x, xb, Wq, Wk, Wv, Wo, Wt, Wto);

    dim3 g2(32, 8);
    gemm_pipe<0><<<g2, 512, 0, stream>>>(xb, Wt, bq, bk, bv, Qw, Kw, Vtw, nullptr);
    attn_fwd<<<768, 512, 0, stream>>>(Qw, Kw, Vtw, ctx);
    dim3 g4(64, 4);
    gemm_pipe<1><<<g4, 512, 0, stream>>>(ctx, Wto, bo, nullptr, nullptr, nullptr, nullptr, nullptr, out);
}

// Round 18
// 119.062 us; speedup vs baseline: 1.0801x; 1.0801x over previous
//
#include <hip/hip_runtime.h>
#include <stdint.h>

#define DM    768
#define NH    12
#define HD    64
#define BATCH 4
#define SEQ   2048
#define NTOK  (BATCH*SEQ)   // 8192
#define NKT   12            // 768 / 64 K-tiles

typedef unsigned int   u32;
typedef unsigned short u16;
using bf16x8 = __attribute__((ext_vector_type(8))) short;
using f32x4  = __attribute__((ext_vector_type(4))) float;

// softmax runs in exp2 domain: Q pre-scaled by (1/8)*log2(e)
#define QSCALE 0.18033688011112042f

__device__ __forceinline__ u16 f2bf(float f) {
    u32 u = __float_as_uint(f);
    u = (u + 0x7FFFu + ((u >> 16) & 1u)) >> 16;
    return (u16)u;
}

__device__ __forceinline__ u32 pkbf(float a, float b) {
    u32 r;
    asm("v_cvt_pk_bf16_f32 %0, %1, %2" : "=v"(r) : "v"(a), "v"(b));
    return r;
}

template <int N>
__device__ __forceinline__ void waitvm() {
    if constexpr (N == 0)      asm volatile("s_waitcnt vmcnt(0)" ::: "memory");
    else if constexpr (N == 4) asm volatile("s_waitcnt vmcnt(4)" ::: "memory");
    else if constexpr (N == 5) asm volatile("s_waitcnt vmcnt(5)" ::: "memory");
    else if constexpr (N == 8) asm volatile("s_waitcnt vmcnt(8)" ::: "memory");
    else if constexpr (N == 9) asm volatile("s_waitcnt vmcnt(9)" ::: "memory");
    else static_assert(N == 0 || N == 4 || N == 5 || N == 8 || N == 9, "add literal");
}

__device__ __forceinline__ void gload_lds16(const void* gptr, void* ldsptr) {
    __builtin_amdgcn_global_load_lds(
        (__attribute__((address_space(1))) const u32*)gptr,
        (__attribute__((address_space(3))) u32*)ldsptr, 16, 0, 0);
}

__device__ __forceinline__ float vmax4(f32x4 v) {
    return fmaxf(fmaxf(v[0], v[1]), fmaxf(v[2], v[3]));
}

// ------- fused prep: x fp32->bf16 (blocks 0..6143) + 4 weight transposes -------
__global__ void prep(const float* __restrict__ x, u16* __restrict__ xb,
                     const float* __restrict__ wq, const float* __restrict__ wk,
                     const float* __restrict__ wv, const float* __restrict__ wo,
                     u16* __restrict__ Wt, u16* __restrict__ Wto) {
    __shared__ float tile[32][33];
    const int blk = blockIdx.x, t = threadIdx.x;
    if (blk < 6144) {                   // x convert: 6144*256 float4 = all of x
        int i = blk * 256 + t;
        float4 v = ((const float4*)x)[i];
        ushort4 o;
        o.x = f2bf(v.x); o.y = f2bf(v.y); o.z = f2bf(v.z); o.w = f2bf(v.w);
        ((ushort4*)xb)[i] = o;
        return;
    }
    int r = blk - 6144;                 // 2304 transpose blocks: z*576 + by*24 + bx
    int z = r / 576;  r -= z * 576;
    int by = r / 24, bx = r - by * 24;
    const float* W = (z == 0) ? wq : (z == 1) ? wk : (z == 2) ? wv : wo;
    u16* D = (z < 3) ? (Wt + (size_t)z * DM * DM) : Wto;
    int tx = t & 31, ty = t >> 5;       // 32 x 8
    int x0 = bx * 32, y0 = by * 32;
    #pragma unroll
    for (int i = 0; i < 32; i += 8)
        tile[ty + i][tx] = W[(size_t)(y0 + ty + i) * DM + x0 + tx];
    __syncthreads();
    #pragma unroll
    for (int i = 0; i < 32; i += 8)
        D[(size_t)(x0 + ty + i) * DM + y0 + tx] = f2bf(tile[tx][ty + i]);
}

// ---- bf16 MFMA GEMM, BK=64, 2-tiles-ahead pipeline with counted vmcnt (T3/T4) ----
// (R16 configuration — MODE0 grid 32x8=256 blocks, MODE1 64x4=256 blocks)
template <int MODE>
__global__ __launch_bounds__(512, 2)
void gemm_pipe(const u16* __restrict__ A, const u16* __restrict__ Bt,
               const float* __restrict__ b0, const float* __restrict__ b1,
               const float* __restrict__ b2,
               u16* __restrict__ Qo, u16* __restrict__ Ko, u16* __restrict__ Vto,
               float* __restrict__ Out)
{
    constexpr int BM = (MODE == 0) ? 256 : 128;
    constexpr int BN = (MODE == 0) ? 288 : 192;
    constexpr int MF = 4;
    constexpr int NF = (MODE == 0) ? 9 : 3;
    constexpr int AL = BM / 64;
    constexpr int BFULL = (MODE == 0) ? 4 : 3;

    __shared__ u16 As[2][BM][64];
    __shared__ u16 Bs[2][BN][64];

    const int t = threadIdx.x;
    const int w = t >> 6, l = t & 63;
    const int l15 = l & 15, lg = l >> 4;
    const int m0 = blockIdx.x * BM;
    const int n0 = blockIdx.y * BN;
    const int waveM = ((MODE == 0) ? (w >> 1) : (w >> 2)) * 64;
    const int waveN = (MODE == 0) ? (w & 1) * 144 : (w & 3) * 48;

    f32x4 zf = {0.f, 0.f, 0.f, 0.f};
    f32x4 acc[MF][NF];
    #pragma unroll
    for (int i = 0; i < MF; ++i)
        #pragma unroll
        for (int j = 0; j < NF; ++j) acc[i][j] = zf;

    const u16* Arow0 = A  + (size_t)m0 * DM;
    const u16* Brow0 = Bt + (size_t)n0 * DM;

    auto stage = [&](int d, int k0) {
        #pragma unroll
        for (int i = 0; i < AL; ++i) {
            int f = i * 512 + t;
            int row = f >> 3, c = f & 7;
            int gc = c ^ (row & 7);
            gload_lds16(Arow0 + (size_t)row * DM + k0 + gc * 8, &As[d][row][c * 8]);
        }
        #pragma unroll
        for (int i = 0; i < BFULL; ++i) {
            int f = i * 512 + t;
            int row = f >> 3, c = f & 7;
            int gc = c ^ (row & 7);
            gload_lds16(Brow0 + (size_t)row * DM + k0 + gc * 8, &Bs[d][row][c * 8]);
        }
        if constexpr (MODE == 0) {
            if (t < 256) {
                int f = 2048 + t;
                int row = f >> 3, c = f & 7;
                int gc = c ^ (row & 7);
                gload_lds16(Brow0 + (size_t)row * DM + k0 + gc * 8, &Bs[d][row][c * 8]);
            }
        }
    };
    auto wait_tile = [&]() {
        if constexpr (MODE == 0) {
            if (w < 4) waitvm<9>(); else waitvm<8>();
        } else {
            waitvm<5>();
        }
    };
    auto phase = [&](int d, int kk) {
        const int ch = ((kk * 4 + lg) ^ (l15 & 7)) * 8;
        bf16x8 af[MF], bfr[NF];
        #pragma unroll
        for (int m = 0; m < MF; ++m)
            af[m] = *(const bf16x8*)&As[d][waveM + m * 16 + l15][ch];
        #pragma unroll
        for (int n = 0; n < NF; ++n)
            bfr[n] = *(const bf16x8*)&Bs[d][waveN + n * 16 + l15][ch];
        __builtin_amdgcn_s_setprio(1);
        #pragma unroll
        for (int m = 0; m < MF; ++m)
            #pragma unroll
            for (int n = 0; n < NF; ++n)
                acc[m][n] = __builtin_amdgcn_mfma_f32_16x16x32_bf16(af[m], bfr[n], acc[m][n], 0, 0, 0);
        __builtin_amdgcn_s_setprio(0);
    };

    stage(0, 0);
    stage(1, 64);

    for (int tt = 0; tt < NKT - 1; ++tt) {
        const int c = tt & 1;
        wait_tile();
        __builtin_amdgcn_s_barrier();
        __builtin_amdgcn_sched_barrier(0);
        phase(c, 0);
        phase(c, 1);
        __builtin_amdgcn_sched_barrier(0);
        __builtin_amdgcn_s_barrier();
        __builtin_amdgcn_sched_barrier(0);
        if (tt + 2 < NKT) stage(c, (tt + 2) * 64);
    }
    {
        waitvm<0>();
        __builtin_amdgcn_s_barrier();
        __builtin_amdgcn_sched_barrier(0);
        phase((NKT - 1) & 1, 0);
        phase((NKT - 1) & 1, 1);
    }

    if (MODE == 1) {
        #pragma unroll
        for (int m = 0; m < MF; ++m) {
            int grow = m0 + waveM + m * 16 + lg * 4;
            #pragma unroll
            for (int n = 0; n < NF; ++n) {
                int gcol = n0 + waveN + n * 16 + l15;
                float bias = b0[gcol];
                #pragma unroll
                for (int r = 0; r < 4; ++r)
                    Out[(size_t)(grow + r) * DM + gcol] = acc[m][n][r] + bias;
            }
        }
    } else {
        #pragma unroll
        for (int m = 0; m < MF; ++m) {
            int grow = m0 + waveM + m * 16 + lg * 4;
            int bb = grow >> 11, ss = grow & 2047;
            #pragma unroll
            for (int n = 0; n < NF; ++n) {
                int nstart = n0 + waveN + n * 16;
                int which = nstart / DM;
                int cbase = nstart - which * DM + l15;
                int h = cbase >> 6, hd = cbase & 63;
                if (which == 0) {
                    float bias = b0[cbase];
                    #pragma unroll
                    for (int r = 0; r < 4; ++r)
                        Qo[(((size_t)bb * NH + h) * SEQ + (ss + r)) * HD + hd] =
                            f2bf((acc[m][n][r] + bias) * QSCALE);
                } else if (which == 1) {
                    float bias = b1[cbase];
                    #pragma unroll
                    for (int r = 0; r < 4; ++r)
                        Ko[(((size_t)bb * NH + h) * SEQ + (ss + r)) * HD + hd] =
                            f2bf(acc[m][n][r] + bias);
                } else {
                    float bias = b2[cbase];
                    u32 lo = pkbf(acc[m][n][0] + bias, acc[m][n][1] + bias);
                    u32 hi = pkbf(acc[m][n][2] + bias, acc[m][n][3] + bias);
                    *(int2*)&Vto[(((size_t)bb * NH + h) * HD + hd) * SEQ + ss] =
                        make_int2((int)lo, (int)hi);
                }
            }
        }
    }
}

// ---------------- causal flash attention v6 (frozen; 57.0-57.3 us) ----------------
__global__ __launch_bounds__(512, 4)
void attn_fwd(const u16* __restrict__ Q, const u16* __restrict__ K_,
              const u16* __restrict__ Vt, u16* __restrict__ ctx)
{
    __shared__ u16 Ks[2][128][64];      // [key][d]
    __shared__ u16 Vs[2][64][128];      // [d][key]

    const int t = threadIdx.x, w = t >> 6, l = t & 63;
    const int l15 = l & 15, lg = l >> 4;
    const int sw = l15 & 7;             // read-side swizzle key
    const int bx = blockIdx.x;
    const int ord = bx / 48;            // ascending => q16 descending (LPT dispatch)
    const int bh  = bx - ord * 48;
    const int q16 = 15 - ord;           // 128-row strip index
    const int b = bh / NH, h = bh - b * NH;
    const int wrow0 = q16 * 128 + w * 16;
    const int niter = q16 + 1;          // 128-key macro-tiles

    const u16* Qp = Q + ((size_t)bh * SEQ + wrow0 + l15) * HD;
    bf16x8 qf0 = *(const bf16x8*)(Qp + lg * 8);
    bf16x8 qf1 = *(const bf16x8*)(Qp + 32 + lg * 8);

    f32x4 zf = {0.f, 0.f, 0.f, 0.f};
    f32x4 acc[4];
    #pragma unroll
    for (int d = 0; d < 4; ++d) acc[d] = zf;
    float mi = -INFINITY, li = 0.f;

    const u16* Kbh = K_ + (size_t)bh * SEQ * HD;
    const u16* Vbh = Vt + (size_t)bh * HD * SEQ;

    auto stage = [&](int d, int j0) {
        #pragma unroll
        for (int i = 0; i < 2; ++i) {
            int f = i * 512 + t;
            int row = f >> 3, c = f & 7;
            gload_lds16(Kbh + (size_t)(j0 + row) * HD + (c ^ (row & 7)) * 8,
                        (u16*)Ks[d] + (size_t)f * 8);
        }
        #pragma unroll
        for (int i = 0; i < 2; ++i) {
            int f = i * 512 + t;
            int r = f >> 4, c = f & 15;
            gload_lds16(Vbh + (size_t)r * SEQ + j0 + (((c & 8) | ((c ^ r) & 7))) * 8,
                        (u16*)Vs[d] + (size_t)f * 8);
        }
    };

    stage(0, 0);
    stage(1, 128);                      // keys 128..255 always exist (S=2048)

    for (int jt = 0; jt < niter; ++jt) {
        const int cur = jt & 1;
        const int j0 = jt << 7;
        if (jt < niter - 1) waitvm<4>(); else waitvm<0>();
        __builtin_amdgcn_s_barrier();
        __builtin_amdgcn_sched_barrier(0);
        const u16 (*Kc)[64]  = Ks[cur];
        const u16 (*Vc)[128] = Vs[cur];
        #pragma unroll
        for (int hk = 0; hk < 2; ++hk) {
            const int j0h = j0 + hk * 64;
            if (j0h <= wrow0 + 15) {    // wave-uniform causal skip per half
                f32x4 s0[4];
                __builtin_amdgcn_s_setprio(1);
                #pragma unroll
                for (int nt = 0; nt < 4; ++nt) {
                    const u16* krow = Kc[hk * 64 + nt * 16 + l15];
                    bf16x8 kf0 = *(const bf16x8*)&krow[(lg ^ sw) * 8];
                    bf16x8 kf1 = *(const bf16x8*)&krow[((4 + lg) ^ sw) * 8];
                    f32x4 a = zf;
                    a = __builtin_amdgcn_mfma_f32_16x16x32_bf16(kf0, qf0, a, 0, 0, 0);
                    a = __builtin_amdgcn_mfma_f32_16x16x32_bf16(kf1, qf1, a, 0, 0, 0);
                    s0[nt] = a;
                }
                __builtin_amdgcn_s_setprio(0);
                if (j0h + 63 > wrow0) { // diagonal region: per-element causal mask
                    #pragma unroll
                    for (int nt = 0; nt < 4; ++nt) {
                        int kb = j0h + nt * 16 + lg * 4;
                        #pragma unroll
                        for (int r = 0; r < 4; ++r)
                            if (kb + r > wrow0 + l15) s0[nt][r] = -INFINITY;
                    }
                }
                float pm = fmaxf(fmaxf(vmax4(s0[0]), vmax4(s0[1])), fmaxf(vmax4(s0[2]), vmax4(s0[3])));
                pm = fmaxf(pm, __shfl_xor(pm, 16));
                pm = fmaxf(pm, __shfl_xor(pm, 32));
                if (!__all(pm <= mi + 8.f)) {   // defer-max (T13)
                    float mn = fmaxf(mi, pm);
                    float so = __builtin_amdgcn_exp2f(mi - mn);
                    mi = mn;
                    li *= so;
                    float a0 = __shfl(so, lg * 4 + 0), a1 = __shfl(so, lg * 4 + 1);
                    float a2 = __shfl(so, lg * 4 + 2), a3 = __shfl(so, lg * 4 + 3);
                    #pragma unroll
                    for (int d = 0; d < 4; ++d) {
                        acc[d][0] *= a0; acc[d][1] *= a1;
                        acc[d][2] *= a2; acc[d][3] *= a3;
                    }
                }
                u32 dwa[8];
                float rs = 0.f;
                #pragma unroll
                for (int nt = 0; nt < 4; ++nt) {
                    float p0 = __builtin_amdgcn_exp2f(s0[nt][0] - mi);
                    float p1 = __builtin_amdgcn_exp2f(s0[nt][1] - mi);
                    float p2 = __builtin_amdgcn_exp2f(s0[nt][2] - mi);
                    float p3 = __builtin_amdgcn_exp2f(s0[nt][3] - mi);
                    rs += (p0 + p1) + (p2 + p3);
                    dwa[nt * 2] = pkbf(p0, p1); dwa[nt * 2 + 1] = pkbf(p2, p3);
                }
                rs += __shfl_xor(rs, 16);
                rs += __shfl_xor(rs, 32);
                li += rs;
                bf16x8 pa0 = __builtin_bit_cast(bf16x8, make_int4((int)dwa[0], (int)dwa[1], (int)dwa[2], (int)dwa[3]));
                bf16x8 pa1 = __builtin_bit_cast(bf16x8, make_int4((int)dwa[4], (int)dwa[5], (int)dwa[6], (int)dwa[7]));
                const int o4 = (lg & 1) * 4, c0 = lg >> 1;
                __builtin_amdgcn_s_setprio(1);
                #pragma unroll
                for (int d = 0; d < 4; ++d) {
                    const u16* vrow = Vc[d * 16 + l15] + hk * 64;
                    int2 v0 = *(const int2*)(vrow + (((c0 + 0) ^ sw) * 8 + o4));
                    int2 v1 = *(const int2*)(vrow + (((c0 + 2) ^ sw) * 8 + o4));
                    int2 v2 = *(const int2*)(vrow + (((c0 + 4) ^ sw) * 8 + o4));
                    int2 v3 = *(const int2*)(vrow + (((c0 + 6) ^ sw) * 8 + o4));
                    bf16x8 vf0 = __builtin_bit_cast(bf16x8, make_int4(v0.x, v0.y, v1.x, v1.y));
                    bf16x8 vf1 = __builtin_bit_cast(bf16x8, make_int4(v2.x, v2.y, v3.x, v3.y));
                    acc[d] = __builtin_amdgcn_mfma_f32_16x16x32_bf16(pa0, vf0, acc[d], 0, 0, 0);
                    acc[d] = __builtin_amdgcn_mfma_f32_16x16x32_bf16(pa1, vf1, acc[d], 0, 0, 0);
                }
                __builtin_amdgcn_s_setprio(0);
            }
        }
        if (jt < niter - 1) {
            __builtin_amdgcn_s_barrier();            // all waves done reading buf cur
            __builtin_amdgcn_sched_barrier(0);
            if (jt + 2 < niter) stage(cur, (jt + 2) << 7);
        }
    }

    // epilogue: ctx [B][S][768] bf16
    float e0 = 1.0f / __shfl(li, lg * 4 + 0), e1 = 1.0f / __shfl(li, lg * 4 + 1);
    float e2 = 1.0f / __shfl(li, lg * 4 + 2), e3 = 1.0f / __shfl(li, lg * 4 + 3);
    #pragma unroll
    for (int r = 0; r < 4; ++r) {
        float f0 = (r == 0) ? e0 : (r == 1) ? e1 : (r == 2) ? e2 : e3;
        int s = wrow0 + lg * 4 + r;
        size_t base = ((size_t)b * SEQ + s) * DM + h * HD;
        #pragma unroll
        for (int d = 0; d < 4; ++d)
            ctx[base + d * 16 + l15] = f2bf(acc[d][r] * f0);
    }
}

extern "C" void kernel_launch(void* const* d_in, const int* in_sizes, int n_in,
                              void* d_out, int out_size, void* d_ws, size_t ws_size,
                              hipStream_t stream) {
    const float* x  = (const float*)d_in[0];
    const float* Wq = (const float*)d_in[1];
    const float* bq = (const float*)d_in[2];
    const float* Wk = (const float*)d_in[3];
    const float* bk = (const float*)d_in[4];
    const float* Wv = (const float*)d_in[5];
    const float* bv = (const float*)d_in[6];
    const float* Wo = (const float*)d_in[7];
    const float* bo = (const float*)d_in[8];
    float* out = (float*)d_out;

    char* ws = (char*)d_ws;
    u16* xb  = (u16*)(ws);                    // 8192*768*2      = 12,582,912
    u16* Wt  = (u16*)(ws + 12582912);         // 2304*768*2      =  3,538,944
    u16* Wto = (u16*)(ws + 16121856);         // 768*768*2       =  1,179,648
    u16* Qw  = (u16*)(ws + 17301504);         // [BH][S][64]     = 12,582,912
    u16* Kw  = (u16*)(ws + 29884416);         // [BH][S][64]     = 12,582,912
    u16* Vtw = (u16*)(ws + 42467328);         // [BH][64][S]     = 12,582,912
    u16* ctx = (u16*)(ws + 55050240);         // [B][S][768]     = 12,582,912

    prep<<<6144 + 2304, 256, 0, stream>>>(x, xb, Wq, Wk, Wv, Wo, Wt, Wto);

    dim3 g2(32, 8);
    gemm_pipe<0><<<g2, 512, 0, stream>>>(xb, Wt, bq, bk, bv, Qw, Kw, Vtw, nullptr);
    attn_fwd<<<768, 512, 0, stream>>>(Qw, Kw, Vtw, ctx);
    dim3 g4(64, 4);
    gemm_pipe<1><<<g4, 512, 0, stream>>>(ctx, Wto, bo, nullptr, nullptr, nullptr, nullptr, nullptr, out);
}